// Round 19
// baseline (96.068 us; speedup 1.0000x reference)
//
#include <hip/hip_runtime.h>

#define N_  2
#define C_  128
#define CR_ 64
#define H_  96
#define W_  96
#define L_  (H_*W_)     // 9216
#define QBLK 128        // q-rows per block = 4 waves x 32 rows
#define KVBLK 64
#define NQB (L_/QBLK)   // 72
#define SPLITS 8
#define TILES_PER ((L_/KVBLK)/SPLITS)   // 18
#define HALVES (TILES_PER*2)            // 36 half-tiles of 32 j
#define NCHUNK (N_*NQB*SPLITS)          // 1152
#define BUFSZ 12288                     // 12KB per half-buffer (K 4KB + V 8KB)
#define LOG2E 1.44269504088896f

typedef short bf16x8 __attribute__((ext_vector_type(8)));
typedef float f32x4  __attribute__((ext_vector_type(4)));

static __device__ __forceinline__ float exp2_fast(float x) {
    return __builtin_amdgcn_exp2f(x);
}

static __device__ __forceinline__ unsigned short f2bf(float f) {
    unsigned u = __builtin_bit_cast(unsigned, f);
    unsigned rounding = 0x7FFFu + ((u >> 16) & 1u);
    return (unsigned short)((u + rounding) >> 16);
}

static __device__ __forceinline__ unsigned cvt_pk_bf16(float lo, float hi) {
    unsigned r;
    asm("v_cvt_pk_bf16_f32 %0, %1, %2" : "=v"(r) : "v"(lo), "v"(hi));
    return r;
}

static __device__ __forceinline__ float bf2f(unsigned short s) {
    return __builtin_bit_cast(float, ((unsigned)s) << 16);
}

// 32-row K permutation: lds row rho holds actual j = sigma32(rho)
// rho bits [b4][b3b2][b1b0] -> j = [b3b2][b4][b1b0]
// => lane (lhi,llo): pf[e] = P[j = 8*lhi + e][i = llo], e = jt*4 + r
static __device__ __forceinline__ int sigma32_(int r) {
    return ((r & 0x0C) << 1) | ((r & 0x10) >> 2) | (r & 3);
}

#define GLD16(G, Ld) __builtin_amdgcn_global_load_lds( \
    (const __attribute__((address_space(1))) void*)(G), \
    (__attribute__((address_space(3))) void*)(Ld), 16, 0, 0)

// ---------------------------------------------------------------------------
// wconv: bf16 weight matrix Wbf[256][128] (w1|w2|wa) + f32 tables — ONCE.
// ---------------------------------------------------------------------------
__global__ __launch_bounds__(256) void wconv_kernel(
    const float* __restrict__ w1, const float* __restrict__ b1, const float* __restrict__ a1,
    const float* __restrict__ w2, const float* __restrict__ b2, const float* __restrict__ a2,
    const float* __restrict__ wa, const float* __restrict__ ba, const float* __restrict__ aa,
    unsigned short* __restrict__ Wbf,
    float* __restrict__ bias, float* __restrict__ alpha, float* __restrict__ scale)
{
    const int idx = blockIdx.x * 256 + threadIdx.x;   // 0 .. 32767
    const int o = idx >> 7, k = idx & 127;
    float wv;
    if (o < 64)       wv = w1[o*C_ + k];
    else if (o < 128) wv = w2[(o-64)*C_ + k];
    else              wv = wa[(o-128)*C_ + k];
    Wbf[idx] = f2bf(wv);
    if (blockIdx.x == 0) {
        int t = threadIdx.x;   // 0..255 == o
        float b, a, sc;
        if (t < 64)       { b = b1[t];       a = a1[0]; sc = LOG2E; }
        else if (t < 128) { b = b2[t-64];    a = a2[0]; sc = 1.0f; }
        else              { b = ba[t-128];   a = aa[0]; sc = 1.0f; }
        bias[t] = b; alpha[t] = a; scale[t] = sc;
    }
}

// ---------------------------------------------------------------------------
// proj_mfma: per block, 64 positions x all 256 outputs via MFMA (unchanged).
// ---------------------------------------------------------------------------
__global__ __launch_bounds__(256) void proj_mfma_kernel(
    const float* __restrict__ x,
    const unsigned short* __restrict__ Wbf,
    const float* __restrict__ bias,
    const float* __restrict__ alpha,
    const float* __restrict__ scale,
    unsigned short* __restrict__ qkv)
{
    __shared__ alignas(16) unsigned char xs[64 * 256];   // 16 KB

    const int blk  = blockIdx.x;                // 0 .. N*(L/64)-1
    const int n    = blk / (L_/64);
    const int i0   = (blk % (L_/64)) * 64;
    const float* xb = x + (size_t)n * C_ * L_;
    const int tid  = threadIdx.x;
    const int wv_  = tid >> 6;
    const int lane = tid & 63;
    const int lhi  = lane >> 4;
    const int llo  = lane & 15;

    {
        const int i = lane;                     // 0..63
        #pragma unroll
        for (int p = 0; p < 8; p++) {
            int c0 = wv_*4 + p*16;
            float v0 = xb[(size_t)(c0+0)*L_ + i0 + i];
            float v1 = xb[(size_t)(c0+1)*L_ + i0 + i];
            float v2 = xb[(size_t)(c0+2)*L_ + i0 + i];
            float v3 = xb[(size_t)(c0+3)*L_ + i0 + i];
            uint2 pk2;
            pk2.x = cvt_pk_bf16(v0, v1);
            pk2.y = cvt_pk_bf16(v2, v3);
            int byte = i*256 + ((((c0 >> 3) ^ (i & 7))) << 4) + (c0 & 7) * 2;
            *reinterpret_cast<uint2*>(xs + byte) = pk2;
        }
    }
    __syncthreads();

    bf16x8 xf[4][4];
    #pragma unroll
    for (int it = 0; it < 4; it++) {
        int i = it*16 + llo;
        #pragma unroll
        for (int ks = 0; ks < 4; ks++) {
            int byte = i*256 + (((ks*4 + lhi) ^ (i & 7)) << 4);
            xf[it][ks] = *reinterpret_cast<const bf16x8*>(xs + byte);
        }
    }

    unsigned short* q_t = qkv;
    unsigned short* k_t = qkv + (size_t)N_ * L_ * CR_;
    unsigned short* v   = qkv + (size_t)2 * N_ * L_ * CR_;
    unsigned short* qtb = q_t + (size_t)n * L_ * CR_;
    unsigned short* ktb = k_t + (size_t)n * L_ * CR_;
    unsigned short* vb  = v   + (size_t)n * C_ * L_;

    #pragma unroll
    for (int oo = 0; oo < 2; oo++) {
        const int ot = wv_*2 + oo;
        const unsigned short* wrow = Wbf + (size_t)(ot*16 + llo) * 128;
        bf16x8 wf[4];
        #pragma unroll
        for (int ks = 0; ks < 4; ks++)
            wf[ks] = *reinterpret_cast<const bf16x8*>(wrow + ks*32 + lhi*8);
        f32x4 acc[4];
        #pragma unroll
        for (int it = 0; it < 4; it++) acc[it] = f32x4{0.f, 0.f, 0.f, 0.f};
        #pragma unroll
        for (int ks = 0; ks < 4; ks++)
            #pragma unroll
            for (int it = 0; it < 4; it++)
                acc[it] = __builtin_amdgcn_mfma_f32_16x16x32_bf16(wf[ks], xf[it][ks], acc[it], 0, 0, 0);

        const int ob = ot*16 + lhi*4;
        const float4 b4 = *reinterpret_cast<const float4*>(bias  + ob);
        const float4 a4 = *reinterpret_cast<const float4*>(alpha + ob);
        const float4 s4 = *reinterpret_cast<const float4*>(scale + ob);
        unsigned short* dst = (ot < 4) ? qtb : ktb;
        const int col = (ot & 3)*16 + lhi*4;
        #pragma unroll
        for (int it = 0; it < 4; it++) {
            int i = i0 + it*16 + llo;
            float y0 = acc[it][0] + b4.x; y0 = (fmaxf(y0,0.f) + a4.x*fminf(y0,0.f))*s4.x;
            float y1 = acc[it][1] + b4.y; y1 = (fmaxf(y1,0.f) + a4.y*fminf(y1,0.f))*s4.y;
            float y2 = acc[it][2] + b4.z; y2 = (fmaxf(y2,0.f) + a4.z*fminf(y2,0.f))*s4.z;
            float y3 = acc[it][3] + b4.w; y3 = (fmaxf(y3,0.f) + a4.w*fminf(y3,0.f))*s4.w;
            uint2 pk2;
            pk2.x = cvt_pk_bf16(y0, y1);
            pk2.y = cvt_pk_bf16(y2, y3);
            *reinterpret_cast<uint2*>(dst + (size_t)i * CR_ + col) = pk2;
        }
    }

    #pragma unroll
    for (int oo = 0; oo < 2; oo++) {
        const int ot2 = wv_*2 + oo;
        const int op  = ot2*16 + llo;
        const unsigned short* wrow = Wbf + (size_t)(128 + op) * 128;
        bf16x8 wf[4];
        #pragma unroll
        for (int ks = 0; ks < 4; ks++)
            wf[ks] = *reinterpret_cast<const bf16x8*>(wrow + ks*32 + lhi*8);
        f32x4 acc[4];
        #pragma unroll
        for (int it = 0; it < 4; it++) acc[it] = f32x4{0.f, 0.f, 0.f, 0.f};
        #pragma unroll
        for (int ks = 0; ks < 4; ks++)
            #pragma unroll
            for (int it = 0; it < 4; it++)
                acc[it] = __builtin_amdgcn_mfma_f32_16x16x32_bf16(xf[it][ks], wf[ks], acc[it], 0, 0, 0);

        const float b = bias[128 + op];
        const float a = alpha[128 + op];
        #pragma unroll
        for (int it = 0; it < 4; it++) {
            float y0 = acc[it][0] + b; y0 = fmaxf(y0,0.f) + a*fminf(y0,0.f);
            float y1 = acc[it][1] + b; y1 = fmaxf(y1,0.f) + a*fminf(y1,0.f);
            float y2 = acc[it][2] + b; y2 = fmaxf(y2,0.f) + a*fminf(y2,0.f);
            float y3 = acc[it][3] + b; y3 = fmaxf(y3,0.f) + a*fminf(y3,0.f);
            uint2 pk2;
            pk2.x = cvt_pk_bf16(y0, y1);
            pk2.y = cvt_pk_bf16(y2, y3);
            *reinterpret_cast<uint2*>(vb + (size_t)op * L_ + i0 + it*16 + lhi*4) = pk2;
        }
    }
}

// ---------------------------------------------------------------------------
// Split-K flash attention, DEPTH-3 COUNTED-VMCNT PIPELINE (T3+T4):
// 36 half-tiles of 32 j; 4x12KB LDS buffers (48KB total, occupancy unchanged);
// raw s_barrier + s_waitcnt vmcnt(9/6/3/0) — prefetch stays in flight across
// barriers. Fixed-shift softmax (m==0), l via ones-MFMA. Geometry: R8's
// verified sigma32 K layout + [64 row][2c x 32 j] V layout.
// o_part layout: [chunk][cg=c/16][i][16e] (coalesced both sides).
// ---------------------------------------------------------------------------
__global__ __launch_bounds__(256, 3) void attn_kernel(
    const unsigned short* __restrict__ qkv,
    unsigned short* __restrict__ o_part,  // [NCHUNK][8][QBLK][16] bf16
    float* __restrict__ l_part)           // [NCHUNK][QBLK]
{
    __shared__ alignas(16) unsigned char kv_lds[4*BUFSZ];

    const unsigned short* q_t = qkv;
    const unsigned short* k_t = qkv + (size_t)N_ * L_ * CR_;
    const unsigned short* v   = qkv + (size_t)2 * N_ * L_ * CR_;

    const int blk  = blockIdx.x;
    const int n    = blk / (NQB * SPLITS);
    const int rem  = blk % (NQB * SPLITS);
    const int qbi  = rem / SPLITS;
    const int s    = rem % SPLITS;
    const int qb   = qbi * QBLK;
    const int tid  = threadIdx.x;
    const int wave = tid >> 6;
    const int lane = tid & 63;
    const int lhi  = lane >> 4;
    const int llo  = lane & 15;

    const int jb_beg = s * TILES_PER * KVBLK;   // start j of this split

    const unsigned short* qtb = q_t + (size_t)n * L_ * CR_;
    const unsigned short* ktb = k_t + (size_t)n * L_ * CR_;
    const unsigned short* vb  = v   + (size_t)n * C_ * L_;

    bf16x8 qf[2][2];
    #pragma unroll
    for (int st = 0; st < 2; st++) {
        int row = qb + wave * 32 + st * 16 + llo;
        #pragma unroll
        for (int ks = 0; ks < 2; ks++)
            qf[st][ks] = *reinterpret_cast<const bf16x8*>(qtb + (size_t)row * CR_ + ks*32 + lhi*8);
    }

    bf16x8 ones_f;
    #pragma unroll
    for (int e = 0; e < 8; e++) ones_f[e] = (short)0x3F80;   // bf16 1.0

    // staging sources (pre-swizzled global, linear LDS dest; 3 GLD16/thread/half)
    // K half: 4KB = 256 granules, 1/thread
    const unsigned short* ksrc;
    {
        int rho = tid >> 3, gb = tid & 7;
        ksrc = ktb + (size_t)sigma32_(rho) * CR_ + (gb ^ (rho & 7)) * 8;
    }
    // V half: 8KB = 512 granules, 2/thread ([64 row][2c x 32 j], XOR granules)
    const unsigned short* vsrc[2];
    #pragma unroll
    for (int q = 0; q < 2; q++) {
        int vi = q*256 + tid;
        int row = vi >> 3, gb = vi & 7;
        int glin = gb ^ (row & 7);
        int c  = row*2 + (glin >> 2);
        int j8 = (glin & 3) * 8;
        vsrc[q] = vb + (size_t)c * L_ + j8;
    }

    #define ISSUE(h_) do {                                                        \
        unsigned char* buf_ = &kv_lds[((h_) & 3) * BUFSZ];                        \
        int j0_ = jb_beg + (h_) * 32;                                             \
        GLD16(ksrc + (size_t)j0_ * CR_, buf_ + wave*1024);                        \
        GLD16(vsrc[0] + j0_, buf_ + 4096 + wave*1024);                            \
        GLD16(vsrc[1] + j0_, buf_ + 8192 + wave*1024);                            \
    } while (0)

    #define WAITBAR(NN) do {                                                      \
        asm volatile("s_waitcnt vmcnt(" #NN ")" ::: "memory");                    \
        asm volatile("s_barrier" ::: "memory");                                   \
    } while (0)

    #define ENDBAR() asm volatile("s_barrier" ::: "memory")

    f32x4 o_acc[2][8];
    #pragma unroll
    for (int st = 0; st < 2; st++)
        #pragma unroll
        for (int ct = 0; ct < 8; ct++) o_acc[st][ct] = f32x4{0.f, 0.f, 0.f, 0.f};
    f32x4 acc_l[2];
    acc_l[0] = f32x4{0.f, 0.f, 0.f, 0.f};
    acc_l[1] = f32x4{0.f, 0.f, 0.f, 0.f};

    // per-lane LDS read constants (R8-verified)
    const int kg0 = ((0*4 + lhi) ^ (llo & 7)) * 16;   // K granule byte, ks=0
    const int kg1 = ((1*4 + lhi) ^ (llo & 7)) * 16;   // ks=1
    const int vgb = (((llo & 1) * 4 + lhi) ^ ((llo >> 1) & 7)) * 16;
    const int vrow_b = (llo >> 1) * 128;

    #define COMPUTE(h_) do {                                                      \
        const unsigned char* buf_ = &kv_lds[((h_) & 3) * BUFSZ];                  \
        const unsigned char* kbuf_ = buf_;                                        \
        const unsigned char* vbuf_ = buf_ + 4096;                                 \
        f32x4 sacc[2][2];                                                         \
        sacc[0][0] = f32x4{0.f,0.f,0.f,0.f}; sacc[0][1] = f32x4{0.f,0.f,0.f,0.f}; \
        sacc[1][0] = f32x4{0.f,0.f,0.f,0.f}; sacc[1][1] = f32x4{0.f,0.f,0.f,0.f}; \
        __builtin_amdgcn_s_setprio(1);                                            \
        _Pragma("unroll")                                                         \
        for (int ks = 0; ks < 2; ks++) {                                          \
            const int kgb = ks ? kg1 : kg0;                                       \
            _Pragma("unroll")                                                     \
            for (int jt = 0; jt < 2; jt++) {                                      \
                bf16x8 kf = *reinterpret_cast<const bf16x8*>(                     \
                    kbuf_ + jt*2048 + llo*128 + kgb);                             \
                sacc[0][jt] = __builtin_amdgcn_mfma_f32_16x16x32_bf16(kf, qf[0][ks], sacc[0][jt], 0, 0, 0); \
                sacc[1][jt] = __builtin_amdgcn_mfma_f32_16x16x32_bf16(kf, qf[1][ks], sacc[1][jt], 0, 0, 0); \
            }                                                                     \
        }                                                                         \
        __builtin_amdgcn_s_setprio(0);                                            \
        unsigned pw0[4], pw1[4];                                                  \
        pw0[0] = cvt_pk_bf16(exp2_fast(sacc[0][0][0]), exp2_fast(sacc[0][0][1])); \
        pw0[1] = cvt_pk_bf16(exp2_fast(sacc[0][0][2]), exp2_fast(sacc[0][0][3])); \
        pw0[2] = cvt_pk_bf16(exp2_fast(sacc[0][1][0]), exp2_fast(sacc[0][1][1])); \
        pw0[3] = cvt_pk_bf16(exp2_fast(sacc[0][1][2]), exp2_fast(sacc[0][1][3])); \
        pw1[0] = cvt_pk_bf16(exp2_fast(sacc[1][0][0]), exp2_fast(sacc[1][0][1])); \
        pw1[1] = cvt_pk_bf16(exp2_fast(sacc[1][0][2]), exp2_fast(sacc[1][0][3])); \
        pw1[2] = cvt_pk_bf16(exp2_fast(sacc[1][1][0]), exp2_fast(sacc[1][1][1])); \
        pw1[3] = cvt_pk_bf16(exp2_fast(sacc[1][1][2]), exp2_fast(sacc[1][1][3])); \
        bf16x8 pf0 = *reinterpret_cast<const bf16x8*>(&pw0[0]);                   \
        bf16x8 pf1 = *reinterpret_cast<const bf16x8*>(&pw1[0]);                   \
        __builtin_amdgcn_s_setprio(1);                                            \
        acc_l[0] = __builtin_amdgcn_mfma_f32_16x16x32_bf16(ones_f, pf0, acc_l[0], 0, 0, 0); \
        acc_l[1] = __builtin_amdgcn_mfma_f32_16x16x32_bf16(ones_f, pf1, acc_l[1], 0, 0, 0); \
        _Pragma("unroll")                                                         \
        for (int ct = 0; ct < 8; ct++) {                                          \
            bf16x8 vf = *reinterpret_cast<const bf16x8*>(                         \
                vbuf_ + ct*1024 + vrow_b + vgb);                                  \
            o_acc[0][ct] = __builtin_amdgcn_mfma_f32_16x16x32_bf16(vf, pf0, o_acc[0][ct], 0, 0, 0); \
            o_acc[1][ct] = __builtin_amdgcn_mfma_f32_16x16x32_bf16(vf, pf1, o_acc[1][ct], 0, 0, 0); \
        }                                                                         \
        __builtin_amdgcn_s_setprio(0);                                            \
    } while (0)

    // ---- prologue: 3 halves in flight (9 loads) ----
    ISSUE(0); ISSUE(1); ISSUE(2);

    // ---- main loop: counted vmcnt, loads never drained to 0 ----
    for (int h = 0; h < HALVES - 3; h++) {
        ISSUE(h + 3);          // 12 outstanding
        WAITBAR(9);            // drain oldest 3 (half h) + sync -> half h visible
        COMPUTE(h);
        ENDBAR();              // all waves done reading buf (h&3) before ISSUE(h+4)
    }
    // ---- epilogue: drain 6 -> 3 -> 0 ----
    WAITBAR(6); COMPUTE(HALVES - 3); ENDBAR();
    WAITBAR(3); COMPUTE(HALVES - 2); ENDBAR();
    WAITBAR(0); COMPUTE(HALVES - 1);

    #undef ISSUE
    #undef WAITBAR
    #undef ENDBAR
    #undef COMPUTE

    // ---- write partials: o_part[blk][cg=ct][i_loc][e=lhi*4..+3] (coalesced) ----
    unsigned short* ob = o_part + (size_t)blk * (QBLK*C_);
    float* lb = l_part + (size_t)blk * QBLK;
    #pragma unroll
    for (int st = 0; st < 2; st++) {
        int i_loc = wave*32 + st*16 + llo;
        #pragma unroll
        for (int ct = 0; ct < 8; ct++) {
            uint2 pkd;
            pkd.x = cvt_pk_bf16(o_acc[st][ct][0], o_acc[st][ct][1]);
            pkd.y = cvt_pk_bf16(o_acc[st][ct][2], o_acc[st][ct][3]);
            *reinterpret_cast<uint2*>(ob + ((size_t)ct * QBLK + i_loc) * 16 + lhi*4) = pkd;
        }
        if (lhi == 0) lb[i_loc] = acc_l[st][0];
    }
}

// ---------------------------------------------------------------------------
// Combine (R18, unchanged): out = (sum_s O_s) / (sum_s l_s) + x.
// ---------------------------------------------------------------------------
__global__ __launch_bounds__(256) void combine_kernel(
    const unsigned short* __restrict__ o_part,
    const float* __restrict__ l_part,
    const float* __restrict__ x,
    float* __restrict__ out)
{
    __shared__ float invl[32];

    const int blk  = blockIdx.x;
    const int part = blk & 3;
    const int qbi  = (blk >> 2) % NQB;
    const int n    = blk / (4 * NQB);
    const int tid  = threadIdx.x;
    const int i0   = part * 32;

    const size_t pbase = (size_t)(n*NQB + qbi) * SPLITS;

    if (tid < 32) {
        float lt = 0.f;
        for (int s = 0; s < SPLITS; s++)
            lt += l_part[(pbase + s) * QBLK + i0 + tid];
        invl[tid] = 1.0f / lt;
    }
    __syncthreads();

    const int il = tid & 31;          // lane-fast i -> coalesced out/x AND o_part
    const int cg = tid >> 5;          // 0..7

    float acc[16];
    #pragma unroll
    for (int k = 0; k < 16; k++) acc[k] = 0.f;

    for (int s = 0; s < SPLITS; s++) {
        const unsigned short* src = o_part + (pbase + s) * (QBLK*C_)
                                  + ((size_t)cg * QBLK + i0 + il) * 16;
        bf16x8 v0 = *reinterpret_cast<const bf16x8*>(src);
        bf16x8 v1 = *reinterpret_cast<const bf16x8*>(src + 8);
        #pragma unroll
        for (int k = 0; k < 8; k++) acc[k]     += bf2f((unsigned short)v0[k]);
        #pragma unroll
        for (int k = 0; k < 8; k++) acc[8 + k] += bf2f((unsigned short)v1[k]);
    }

    const float nv = invl[il];
    const int ig = qbi*QBLK + i0 + il;
    const float* xb = x   + (size_t)n * C_ * L_;
    float*       ob = out + (size_t)n * C_ * L_;
    #pragma unroll
    for (int k = 0; k < 16; k++) {
        int c = cg*16 + k;
        ob[(size_t)c * L_ + ig] = acc[k] * nv + xb[(size_t)c * L_ + ig];
    }
}

extern "C" void kernel_launch(void* const* d_in, const int* in_sizes, int n_in,
                              void* d_out, int out_size, void* d_ws, size_t ws_size,
                              hipStream_t stream) {
    const float* x  = (const float*)d_in[0];
    const float* w1 = (const float*)d_in[1];
    const float* b1 = (const float*)d_in[2];
    const float* a1 = (const float*)d_in[3];
    const float* w2 = (const float*)d_in[4];
    const float* b2 = (const float*)d_in[5];
    const float* a2 = (const float*)d_in[6];
    const float* wa = (const float*)d_in[7];
    const float* ba = (const float*)d_in[8];
    const float* aa = (const float*)d_in[9];
    float* out = (float*)d_out;

    unsigned short* qkv = (unsigned short*)d_ws;
    size_t qkv_bytes = ((size_t)2*N_*L_*CR_ + (size_t)N_*C_*L_) * 2;
    size_t off = (qkv_bytes + 255) & ~(size_t)255;

    unsigned short* o_part = (unsigned short*)((char*)d_ws + off);
    size_t o_elems = (size_t)NCHUNK * QBLK * C_;
    float* l_part = (float*)(o_part + o_elems);
    float* tail   = l_part + (size_t)NCHUNK * QBLK;
    unsigned short* Wbf = (unsigned short*)tail;         // 256*128 bf16 = 64 KB
    float* bias  = (float*)(Wbf + 256*128);
    float* alpha = bias + 256;
    float* scale = alpha + 256;

    wconv_kernel<<<128, 256, 0, stream>>>(w1, b1, a1, w2, b2, a2, wa, ba, aa,
                                          Wbf, bias, alpha, scale);
    proj_mfma_kernel<<<N_ * (L_/64), 256, 0, stream>>>(x, Wbf, bias, alpha, scale, qkv);
    attn_kernel<<<NCHUNK, 256, 0, stream>>>(qkv, o_part, l_part);
    combine_kernel<<<N_ * NQB * 4, 256, 0, stream>>>(o_part, l_part, x, out);
}

// Round 20
// 93.810 us; speedup vs baseline: 1.0241x; 1.0241x over previous
//
#include <hip/hip_runtime.h>

#define N_  2
#define C_  128
#define CR_ 64
#define H_  96
#define W_  96
#define L_  (H_*W_)     // 9216
#define QBLK 128        // q-rows per block = 4 waves x 32 rows
#define KVBLK 64
#define NQB (L_/QBLK)   // 72
#define SPLITS 8
#define TILES_PER ((L_/KVBLK)/SPLITS)   // 18
#define NCHUNK (N_*NQB*SPLITS)          // 1152
#define LOG2E 1.44269504088896f

typedef short bf16x8 __attribute__((ext_vector_type(8)));
typedef float f32x4  __attribute__((ext_vector_type(4)));

static __device__ __forceinline__ float exp2_fast(float x) {
    return __builtin_amdgcn_exp2f(x);
}

static __device__ __forceinline__ unsigned short f2bf(float f) {
    unsigned u = __builtin_bit_cast(unsigned, f);
    unsigned rounding = 0x7FFFu + ((u >> 16) & 1u);
    return (unsigned short)((u + rounding) >> 16);
}

static __device__ __forceinline__ unsigned cvt_pk_bf16(float lo, float hi) {
    unsigned r;
    asm("v_cvt_pk_bf16_f32 %0, %1, %2" : "=v"(r) : "v"(lo), "v"(hi));
    return r;
}

static __device__ __forceinline__ float bf2f(unsigned short s) {
    return __builtin_bit_cast(float, ((unsigned)s) << 16);
}

// K-row permutation (KVBLK=64): lds row rho holds actual j = sigma(rho)
static __device__ __forceinline__ int sigma_(int r) {
    return (r & 0x23) | ((r & 0x0C) << 1) | ((r & 0x10) >> 2);
}

#define GLD16(G, Ld) __builtin_amdgcn_global_load_lds( \
    (const __attribute__((address_space(1))) void*)(G), \
    (__attribute__((address_space(3))) void*)(Ld), 16, 0, 0)

// ---------------------------------------------------------------------------
// wconv: bf16 weight matrix Wbf[256][128] (w1|w2|wa) + f32 tables — ONCE.
// ---------------------------------------------------------------------------
__global__ __launch_bounds__(256) void wconv_kernel(
    const float* __restrict__ w1, const float* __restrict__ b1, const float* __restrict__ a1,
    const float* __restrict__ w2, const float* __restrict__ b2, const float* __restrict__ a2,
    const float* __restrict__ wa, const float* __restrict__ ba, const float* __restrict__ aa,
    unsigned short* __restrict__ Wbf,
    float* __restrict__ bias, float* __restrict__ alpha, float* __restrict__ scale)
{
    const int idx = blockIdx.x * 256 + threadIdx.x;   // 0 .. 32767
    const int o = idx >> 7, k = idx & 127;
    float wv;
    if (o < 64)       wv = w1[o*C_ + k];
    else if (o < 128) wv = w2[(o-64)*C_ + k];
    else              wv = wa[(o-128)*C_ + k];
    Wbf[idx] = f2bf(wv);
    if (blockIdx.x == 0) {
        int t = threadIdx.x;   // 0..255 == o
        float b, a, sc;
        if (t < 64)       { b = b1[t];       a = a1[0]; sc = LOG2E; }
        else if (t < 128) { b = b2[t-64];    a = a2[0]; sc = 1.0f; }
        else              { b = ba[t-128];   a = aa[0]; sc = 1.0f; }
        bias[t] = b; alpha[t] = a; scale[t] = sc;
    }
}

// ---------------------------------------------------------------------------
// proj_mfma: per block, 64 positions x all 256 outputs via MFMA.
// ---------------------------------------------------------------------------
__global__ __launch_bounds__(256) void proj_mfma_kernel(
    const float* __restrict__ x,
    const unsigned short* __restrict__ Wbf,
    const float* __restrict__ bias,
    const float* __restrict__ alpha,
    const float* __restrict__ scale,
    unsigned short* __restrict__ qkv)
{
    __shared__ alignas(16) unsigned char xs[64 * 256];   // 16 KB

    const int blk  = blockIdx.x;                // 0 .. N*(L/64)-1
    const int n    = blk / (L_/64);
    const int i0   = (blk % (L_/64)) * 64;
    const float* xb = x + (size_t)n * C_ * L_;
    const int tid  = threadIdx.x;
    const int wv_  = tid >> 6;
    const int lane = tid & 63;
    const int lhi  = lane >> 4;
    const int llo  = lane & 15;

    // stage + transpose x[c][i] -> xs[i][c] (bf16, swizzled)
    {
        const int i = lane;                     // 0..63
        #pragma unroll
        for (int p = 0; p < 8; p++) {
            int c0 = wv_*4 + p*16;
            float v0 = xb[(size_t)(c0+0)*L_ + i0 + i];
            float v1 = xb[(size_t)(c0+1)*L_ + i0 + i];
            float v2 = xb[(size_t)(c0+2)*L_ + i0 + i];
            float v3 = xb[(size_t)(c0+3)*L_ + i0 + i];
            uint2 pk2;
            pk2.x = cvt_pk_bf16(v0, v1);
            pk2.y = cvt_pk_bf16(v2, v3);
            int byte = i*256 + ((((c0 >> 3) ^ (i & 7))) << 4) + (c0 & 7) * 2;
            *reinterpret_cast<uint2*>(xs + byte) = pk2;
        }
    }
    __syncthreads();

    bf16x8 xf[4][4];
    #pragma unroll
    for (int it = 0; it < 4; it++) {
        int i = it*16 + llo;
        #pragma unroll
        for (int ks = 0; ks < 4; ks++) {
            int byte = i*256 + (((ks*4 + lhi) ^ (i & 7)) << 4);
            xf[it][ks] = *reinterpret_cast<const bf16x8*>(xs + byte);
        }
    }

    unsigned short* q_t = qkv;
    unsigned short* k_t = qkv + (size_t)N_ * L_ * CR_;
    unsigned short* v   = qkv + (size_t)2 * N_ * L_ * CR_;
    unsigned short* qtb = q_t + (size_t)n * L_ * CR_;
    unsigned short* ktb = k_t + (size_t)n * L_ * CR_;
    unsigned short* vb  = v   + (size_t)n * C_ * L_;

    // ---- pass 1: q (ot<4) and k (ot>=4); D[o][i] ----
    #pragma unroll
    for (int oo = 0; oo < 2; oo++) {
        const int ot = wv_*2 + oo;
        const unsigned short* wrow = Wbf + (size_t)(ot*16 + llo) * 128;
        bf16x8 wf[4];
        #pragma unroll
        for (int ks = 0; ks < 4; ks++)
            wf[ks] = *reinterpret_cast<const bf16x8*>(wrow + ks*32 + lhi*8);
        f32x4 acc[4];
        #pragma unroll
        for (int it = 0; it < 4; it++) acc[it] = f32x4{0.f, 0.f, 0.f, 0.f};
        #pragma unroll
        for (int ks = 0; ks < 4; ks++)
            #pragma unroll
            for (int it = 0; it < 4; it++)
                acc[it] = __builtin_amdgcn_mfma_f32_16x16x32_bf16(wf[ks], xf[it][ks], acc[it], 0, 0, 0);

        const int ob = ot*16 + lhi*4;
        const float4 b4 = *reinterpret_cast<const float4*>(bias  + ob);
        const float4 a4 = *reinterpret_cast<const float4*>(alpha + ob);
        const float4 s4 = *reinterpret_cast<const float4*>(scale + ob);
        unsigned short* dst = (ot < 4) ? qtb : ktb;
        const int col = (ot & 3)*16 + lhi*4;
        #pragma unroll
        for (int it = 0; it < 4; it++) {
            int i = i0 + it*16 + llo;
            float y0 = acc[it][0] + b4.x; y0 = (fmaxf(y0,0.f) + a4.x*fminf(y0,0.f))*s4.x;
            float y1 = acc[it][1] + b4.y; y1 = (fmaxf(y1,0.f) + a4.y*fminf(y1,0.f))*s4.y;
            float y2 = acc[it][2] + b4.z; y2 = (fmaxf(y2,0.f) + a4.z*fminf(y2,0.f))*s4.z;
            float y3 = acc[it][3] + b4.w; y3 = (fmaxf(y3,0.f) + a4.w*fminf(y3,0.f))*s4.w;
            uint2 pk2;
            pk2.x = cvt_pk_bf16(y0, y1);
            pk2.y = cvt_pk_bf16(y2, y3);
            *reinterpret_cast<uint2*>(dst + (size_t)i * CR_ + col) = pk2;
        }
    }

    // ---- pass 2: v; D[i][o'] ----
    #pragma unroll
    for (int oo = 0; oo < 2; oo++) {
        const int ot2 = wv_*2 + oo;
        const int op  = ot2*16 + llo;
        const unsigned short* wrow = Wbf + (size_t)(128 + op) * 128;
        bf16x8 wf[4];
        #pragma unroll
        for (int ks = 0; ks < 4; ks++)
            wf[ks] = *reinterpret_cast<const bf16x8*>(wrow + ks*32 + lhi*8);
        f32x4 acc[4];
        #pragma unroll
        for (int it = 0; it < 4; it++) acc[it] = f32x4{0.f, 0.f, 0.f, 0.f};
        #pragma unroll
        for (int ks = 0; ks < 4; ks++)
            #pragma unroll
            for (int it = 0; it < 4; it++)
                acc[it] = __builtin_amdgcn_mfma_f32_16x16x32_bf16(xf[it][ks], wf[ks], acc[it], 0, 0, 0);

        const float b = bias[128 + op];
        const float a = alpha[128 + op];
        #pragma unroll
        for (int it = 0; it < 4; it++) {
            float y0 = acc[it][0] + b; y0 = fmaxf(y0,0.f) + a*fminf(y0,0.f);
            float y1 = acc[it][1] + b; y1 = fmaxf(y1,0.f) + a*fminf(y1,0.f);
            float y2 = acc[it][2] + b; y2 = fmaxf(y2,0.f) + a*fminf(y2,0.f);
            float y3 = acc[it][3] + b; y3 = fmaxf(y3,0.f) + a*fminf(y3,0.f);
            uint2 pk2;
            pk2.x = cvt_pk_bf16(y0, y1);
            pk2.y = cvt_pk_bf16(y2, y3);
            *reinterpret_cast<uint2*>(vb + (size_t)op * L_ + i0 + it*16 + lhi*4) = pk2;
        }
    }
}

// ---------------------------------------------------------------------------
// Split-K flash attention (R18 champion): FIXED-SHIFT softmax (m==0),
// static grid, 4 waves x 32 q-rows, KVBLK=64, dbuf 48KB LDS, l via ones-MFMA.
// o_part layout: [chunk][cg=c/16][i][16e] -> fully coalesced writes AND reads.
// ---------------------------------------------------------------------------
__global__ __launch_bounds__(256, 3) void attn_kernel(
    const unsigned short* __restrict__ qkv,
    unsigned short* __restrict__ o_part,  // [NCHUNK][8][QBLK][16] bf16
    float* __restrict__ l_part)           // [NCHUNK][QBLK]
{
    __shared__ alignas(16) unsigned char kv_lds[2][24*1024];

    const unsigned short* q_t = qkv;
    const unsigned short* k_t = qkv + (size_t)N_ * L_ * CR_;
    const unsigned short* v   = qkv + (size_t)2 * N_ * L_ * CR_;

    const int blk  = blockIdx.x;
    const int n    = blk / (NQB * SPLITS);
    const int rem  = blk % (NQB * SPLITS);
    const int qbi  = rem / SPLITS;
    const int s    = rem % SPLITS;
    const int qb   = qbi * QBLK;
    const int tid  = threadIdx.x;
    const int wave = tid >> 6;
    const int lane = tid & 63;
    const int lhi  = lane >> 4;
    const int llo  = lane & 15;

    const int jb_beg = s * TILES_PER * KVBLK;
    const int jb_end = jb_beg + TILES_PER * KVBLK;

    const unsigned short* qtb = q_t + (size_t)n * L_ * CR_;
    const unsigned short* ktb = k_t + (size_t)n * L_ * CR_;
    const unsigned short* vb  = v   + (size_t)n * C_ * L_;

    bf16x8 qf[2][2];
    #pragma unroll
    for (int st = 0; st < 2; st++) {
        int row = qb + wave * 32 + st * 16 + llo;
        #pragma unroll
        for (int ks = 0; ks < 2; ks++)
            qf[st][ks] = *reinterpret_cast<const bf16x8*>(qtb + (size_t)row * CR_ + ks*32 + lhi*8);
    }

    bf16x8 ones_f;
    #pragma unroll
    for (int e = 0; e < 8; e++) ones_f[e] = (short)0x3F80;   // bf16 1.0

    const int l8 = lane >> 3;
    const int l7 = (lane & 7) * 16;
    const int rho0 = wave*16 + l8;
    const int rho1 = rho0 + 8;
    const unsigned short* kbase0 = ktb + (size_t)sigma_(rho0) * CR_ + ((l7 ^ ((rho0 & 7) << 4)) >> 1);
    const unsigned short* kbase1 = ktb + (size_t)sigma_(rho1) * CR_ + ((l7 ^ ((rho1 & 7) << 4)) >> 1);
    const unsigned short* vbase[4];
    #pragma unroll
    for (int vt = 0; vt < 4; vt++) {
        int c = wave*32 + vt*8 + l8;
        vbase[vt] = vb + (size_t)c * L_ + ((l7 ^ (l8 << 4)) >> 1);
    }

    #define STAGE(b, jb_) do {                                                   \
        GLD16(kbase0 + (size_t)(jb_) * CR_, &kv_lds[b][(wave*2+0)*1024 + 0]);    \
        GLD16(kbase1 + (size_t)(jb_) * CR_, &kv_lds[b][(wave*2+1)*1024 + 0]);    \
        GLD16(vbase[0] + (jb_), &kv_lds[b][8192 + (wave*4+0)*1024]);             \
        GLD16(vbase[1] + (jb_), &kv_lds[b][8192 + (wave*4+1)*1024]);             \
        GLD16(vbase[2] + (jb_), &kv_lds[b][8192 + (wave*4+2)*1024]);             \
        GLD16(vbase[3] + (jb_), &kv_lds[b][8192 + (wave*4+3)*1024]);             \
    } while (0)

    f32x4 o_acc[2][8];
    #pragma unroll
    for (int st = 0; st < 2; st++)
        #pragma unroll
        for (int ct = 0; ct < 8; ct++) o_acc[st][ct] = f32x4{0.f, 0.f, 0.f, 0.f};
    f32x4 acc_l[2];
    acc_l[0] = f32x4{0.f, 0.f, 0.f, 0.f};
    acc_l[1] = f32x4{0.f, 0.f, 0.f, 0.f};

    int cur = 0;
    STAGE(0, jb_beg);
    __syncthreads();

    for (int jb = jb_beg; jb < jb_end; jb += KVBLK) {
        if (jb + KVBLK < jb_end) STAGE(cur ^ 1, jb + KVBLK);

        const unsigned char* kbuf = &kv_lds[cur][0];
        const unsigned char* vbuf = &kv_lds[cur][8192];

        // ---- S^T = K . Q^T ----
        f32x4 sacc[2][4];
        #pragma unroll
        for (int st = 0; st < 2; st++)
            #pragma unroll
            for (int jt = 0; jt < 4; jt++) sacc[st][jt] = f32x4{0.f, 0.f, 0.f, 0.f};
        __builtin_amdgcn_s_setprio(1);
        #pragma unroll
        for (int ks = 0; ks < 2; ks++) {
            #pragma unroll
            for (int jt = 0; jt < 4; jt++) {
                int rho  = jt*16 + llo;
                int colb = ks*64 + lhi*16;
                bf16x8 kf = *reinterpret_cast<const bf16x8*>(
                    kbuf + rho*128 + (colb ^ ((rho & 7) << 4)));
                sacc[0][jt] = __builtin_amdgcn_mfma_f32_16x16x32_bf16(kf, qf[0][ks], sacc[0][jt], 0, 0, 0);
                sacc[1][jt] = __builtin_amdgcn_mfma_f32_16x16x32_bf16(kf, qf[1][ks], sacc[1][jt], 0, 0, 0);
            }
        }
        __builtin_amdgcn_s_setprio(0);

        // ---- P = exp2(S) in place (fixed shift m=0) ----
        #pragma unroll
        for (int st = 0; st < 2; st++)
            #pragma unroll
            for (int jt = 0; jt < 4; jt++)
                #pragma unroll
                for (int r = 0; r < 4; r++)
                    sacc[st][jt][r] = exp2_fast(sacc[st][jt][r]);

        // ---- PV (+ l via ones-MFMA), cvt_pk inline ----
        __builtin_amdgcn_s_setprio(1);
        #pragma unroll
        for (int ks = 0; ks < 2; ks++) {
            unsigned pw0[4], pw1[4];
            pw0[0] = cvt_pk_bf16(sacc[0][2*ks][0],   sacc[0][2*ks][1]);
            pw0[1] = cvt_pk_bf16(sacc[0][2*ks][2],   sacc[0][2*ks][3]);
            pw0[2] = cvt_pk_bf16(sacc[0][2*ks+1][0], sacc[0][2*ks+1][1]);
            pw0[3] = cvt_pk_bf16(sacc[0][2*ks+1][2], sacc[0][2*ks+1][3]);
            pw1[0] = cvt_pk_bf16(sacc[1][2*ks][0],   sacc[1][2*ks][1]);
            pw1[1] = cvt_pk_bf16(sacc[1][2*ks][2],   sacc[1][2*ks][3]);
            pw1[2] = cvt_pk_bf16(sacc[1][2*ks+1][0], sacc[1][2*ks+1][1]);
            pw1[3] = cvt_pk_bf16(sacc[1][2*ks+1][2], sacc[1][2*ks+1][3]);
            bf16x8 pf0 = *reinterpret_cast<const bf16x8*>(&pw0[0]);
            bf16x8 pf1 = *reinterpret_cast<const bf16x8*>(&pw1[0]);
            acc_l[0] = __builtin_amdgcn_mfma_f32_16x16x32_bf16(ones_f, pf0, acc_l[0], 0, 0, 0);
            acc_l[1] = __builtin_amdgcn_mfma_f32_16x16x32_bf16(ones_f, pf1, acc_l[1], 0, 0, 0);
            #pragma unroll
            for (int ct = 0; ct < 8; ct++) {
                int c = ct*16 + llo;
                int colb = ks*64 + lhi*16;
                bf16x8 vf = *reinterpret_cast<const bf16x8*>(
                    vbuf + c*128 + (colb ^ ((c & 7) << 4)));
                o_acc[0][ct] = __builtin_amdgcn_mfma_f32_16x16x32_bf16(vf, pf0, o_acc[0][ct], 0, 0, 0);
                o_acc[1][ct] = __builtin_amdgcn_mfma_f32_16x16x32_bf16(vf, pf1, o_acc[1][ct], 0, 0, 0);
            }
        }
        __builtin_amdgcn_s_setprio(0);

        __syncthreads();
        cur ^= 1;
    }
    #undef STAGE

    // ---- write partials: o_part[blk][cg=ct][i_loc][e=lhi*4..+3] (coalesced) ----
    unsigned short* ob = o_part + (size_t)blk * (QBLK*C_);
    float* lb = l_part + (size_t)blk * QBLK;
    #pragma unroll
    for (int st = 0; st < 2; st++) {
        int i_loc = wave*32 + st*16 + llo;
        #pragma unroll
        for (int ct = 0; ct < 8; ct++) {
            uint2 pkd;
            pkd.x = cvt_pk_bf16(o_acc[st][ct][0], o_acc[st][ct][1]);
            pkd.y = cvt_pk_bf16(o_acc[st][ct][2], o_acc[st][ct][3]);
            *reinterpret_cast<uint2*>(ob + ((size_t)ct * QBLK + i_loc) * 16 + lhi*4) = pkd;
        }
        if (lhi == 0) lb[i_loc] = acc_l[st][0];
    }
}

// ---------------------------------------------------------------------------
// Combine: out = (sum_s O_s) / (sum_s l_s) + x.
// o_part layout [chunk][cg][i][16e]: reads fully coalesced with the
// write-coalesced (il=tid&31, cg=tid>>5) mapping.
// ---------------------------------------------------------------------------
__global__ __launch_bounds__(256) void combine_kernel(
    const unsigned short* __restrict__ o_part,
    const float* __restrict__ l_part,
    const float* __restrict__ x,
    float* __restrict__ out)
{
    __shared__ float invl[32];

    const int blk  = blockIdx.x;
    const int part = blk & 3;
    const int qbi  = (blk >> 2) % NQB;
    const int n    = blk / (4 * NQB);
    const int tid  = threadIdx.x;
    const int i0   = part * 32;

    const size_t pbase = (size_t)(n*NQB + qbi) * SPLITS;

    if (tid < 32) {
        float lt = 0.f;
        for (int s = 0; s < SPLITS; s++)
            lt += l_part[(pbase + s) * QBLK + i0 + tid];
        invl[tid] = 1.0f / lt;
    }
    __syncthreads();

    const int il = tid & 31;          // lane-fast i -> coalesced out/x AND o_part
    const int cg = tid >> 5;          // 0..7

    float acc[16];
    #pragma unroll
    for (int k = 0; k < 16; k++) acc[k] = 0.f;

    for (int s = 0; s < SPLITS; s++) {
        const unsigned short* src = o_part + (pbase + s) * (QBLK*C_)
                                  + ((size_t)cg * QBLK + i0 + il) * 16;
        bf16x8 v0 = *reinterpret_cast<const bf16x8*>(src);
        bf16x8 v1 = *reinterpret_cast<const bf16x8*>(src + 8);
        #pragma unroll
        for (int k = 0; k < 8; k++) acc[k]     += bf2f((unsigned short)v0[k]);
        #pragma unroll
        for (int k = 0; k < 8; k++) acc[8 + k] += bf2f((unsigned short)v1[k]);
    }

    const float nv = invl[il];
    const int ig = qbi*QBLK + i0 + il;
    const float* xb = x   + (size_t)n * C_ * L_;
    float*       ob = out + (size_t)n * C_ * L_;
    #pragma unroll
    for (int k = 0; k < 16; k++) {
        int c = cg*16 + k;
        ob[(size_t)c * L_ + ig] = acc[k] * nv + xb[(size_t)c * L_ + ig];
    }
}

extern "C" void kernel_launch(void* const* d_in, const int* in_sizes, int n_in,
                              void* d_out, int out_size, void* d_ws, size_t ws_size,
                              hipStream_t stream) {
    const float* x  = (const float*)d_in[0];
    const float* w1 = (const float*)d_in[1];
    const float* b1 = (const float*)d_in[2];
    const float* a1 = (const float*)d_in[3];
    const float* w2 = (const float*)d_in[4];
    const float* b2 = (const float*)d_in[5];
    const float* a2 = (const float*)d_in[6];
    const float* wa = (const float*)d_in[7];
    const float* ba = (const float*)d_in[8];
    const float* aa = (const float*)d_in[9];
    float* out = (float*)d_out;

    unsigned short* qkv = (unsigned short*)d_ws;
    size_t qkv_bytes = ((size_t)2*N_*L_*CR_ + (size_t)N_*C_*L_) * 2;
    size_t off = (qkv_bytes + 255) & ~(size_t)255;

    unsigned short* o_part = (unsigned short*)((char*)d_ws + off);
    size_t o_elems = (size_t)NCHUNK * QBLK * C_;
    float* l_part = (float*)(o_part + o_elems);
    float* tail   = l_part + (size_t)NCHUNK * QBLK;
    unsigned short* Wbf = (unsigned short*)tail;         // 256*128 bf16 = 64 KB
    float* bias  = (float*)(Wbf + 256*128);
    float* alpha = bias + 256;
    float* scale = alpha + 256;

    wconv_kernel<<<128, 256, 0, stream>>>(w1, b1, a1, w2, b2, a2, wa, ba, aa,
                                          Wbf, bias, alpha, scale);
    proj_mfma_kernel<<<N_ * (L_/64), 256, 0, stream>>>(x, Wbf, bias, alpha, scale, qkv);
    attn_kernel<<<NCHUNK, 256, 0, stream>>>(qkv, o_part, l_part);
    combine_kernel<<<N_ * NQB * 4, 256, 0, stream>>>(o_part, l_part, x, out);
}